// Round 2
// baseline (285.831 us; speedup 1.0000x reference)
//
#include <hip/hip_runtime.h>
#include <stdint.h>

typedef unsigned short u16;
typedef __attribute__((ext_vector_type(8))) short s16x8;   // 8 bf16 MFMA frag
typedef __attribute__((ext_vector_type(4))) float f32x4;   // MFMA accumulator
typedef __attribute__((ext_vector_type(4))) unsigned short u16x4;
typedef __attribute__((ext_vector_type(8))) unsigned short u16x8;

#define NHEADS 16
#define DMODEL 1024
#define DHEAD 64
#define SEQ 2048
#define NBATCH 2
#define MROWS (NBATCH * SEQ)   /* 4096 */
#define NQK 2048               /* Q,K output cols */

__device__ __forceinline__ u16 f2bf(float x) {
  union { float f; unsigned u; } v; v.f = x;
  return (u16)((v.u + 0x7fffu + ((v.u >> 16) & 1u)) >> 16);  // RNE
}
__device__ __forceinline__ float bf2f(u16 h) {
  union { unsigned u; float f; } v; v.u = ((unsigned)h) << 16; return v.f;
}

__device__ __forceinline__ void gload_lds16(const void* g, void* l) {
  __builtin_amdgcn_global_load_lds(
      (const __attribute__((address_space(1))) void*)g,
      (__attribute__((address_space(3))) void*)l, 16, 0, 0);
}

// ---------------- prep kernels ----------------

// residual fp32 -> bf16 hi/lo planes, 8 elems/thread
__global__ __launch_bounds__(256) void pack_x_kernel(const float* __restrict__ X,
                                                     u16* __restrict__ Xhi,
                                                     u16* __restrict__ Xlo) {
  int i = blockIdx.x * 256 + threadIdx.x;
  const f32x4* xv = (const f32x4*)(X + (size_t)i * 8);
  f32x4 a = xv[0], b = xv[1];
  float vals[8] = {a[0], a[1], a[2], a[3], b[0], b[1], b[2], b[3]};
  u16x8 oh, ol;
#pragma unroll
  for (int j = 0; j < 8; ++j) {
    u16 h = f2bf(vals[j]);
    oh[j] = h;
    ol[j] = f2bf(vals[j] - bf2f(h));
  }
  *(u16x8*)(Xhi + (size_t)i * 8) = oh;
  *(u16x8*)(Xlo + (size_t)i * 8) = ol;
}

// W_{Q,K,V}[h][m][d] fp32 -> Wt[n][m] hi/lo, n = qkv*1024 + h*64 + d
__global__ __launch_bounds__(256) void pack_wqkv_kernel(const float* __restrict__ WQ,
                                                        const float* __restrict__ WK,
                                                        const float* __restrict__ WV,
                                                        u16* __restrict__ Whi,
                                                        u16* __restrict__ Wlo) {
  int n = blockIdx.x;                                // 3072 blocks
  int qkv = n >> 10, hd = n & 1023, h = hd >> 6, d = hd & 63;
  const float* W = (qkv == 0) ? WQ : ((qkv == 1) ? WK : WV);
  const float* src = W + (size_t)h * DMODEL * DHEAD + d;
  int m0 = threadIdx.x * 4;
  u16x4 oh, ol;
#pragma unroll
  for (int j = 0; j < 4; ++j) {
    float v = src[(size_t)(m0 + j) * DHEAD];
    u16 hh = f2bf(v);
    oh[j] = hh;
    ol[j] = f2bf(v - bf2f(hh));
  }
  *(u16x4*)(Whi + (size_t)n * DMODEL + m0) = oh;
  *(u16x4*)(Wlo + (size_t)n * DMODEL + m0) = ol;
}

// W_O[e][m] fp32 -> Wt_o[m][e] bf16 (B^T layout)
__global__ __launch_bounds__(256) void pack_wo_kernel(const float* __restrict__ WO,
                                                      u16* __restrict__ Wt) {
  int m = blockIdx.x;
  int e0 = threadIdx.x * 4;
  u16x4 o;
#pragma unroll
  for (int j = 0; j < 4; ++j) o[j] = f2bf(WO[(size_t)(e0 + j) * DMODEL + m]);
  *(u16x4*)(Wt + (size_t)m * DMODEL + e0) = o;
}

// ---------------- split-precision GEMM for Q,K ----------------
// C[M][N] = (Ahi+Alo)(Bhi+Blo)^T (3-term), 128x128 tile, BK=32, K=1024, N=2048
__global__ __launch_bounds__(256, 2) void gemm_qk(
    const u16* __restrict__ Ahi, const u16* __restrict__ Alo,
    const u16* __restrict__ Bhi, const u16* __restrict__ Blo,
    const float* __restrict__ bq, const float* __restrict__ bk,
    u16* __restrict__ Qhi, u16* __restrict__ Qlo,
    u16* __restrict__ Khi, u16* __restrict__ Klo) {
  __shared__ u16 lds[2][16384];  // [buf][Ahi|Alo|Bhi|Blo] 4096 u16 each
  const int tid = threadIdx.x;
  const int wid = tid >> 6, lane = tid & 63, lr = lane & 15, lg = lane >> 4;
  const int wr = wid >> 1, wc = wid & 1;
  const int brow = blockIdx.y * 128, bcol = blockIdx.x * 128;

  f32x4 acc[4][4];
#pragma unroll
  for (int i = 0; i < 4; ++i)
#pragma unroll
    for (int j = 0; j < 4; ++j) acc[i][j] = (f32x4){0.f, 0.f, 0.f, 0.f};

#define STAGE_QK(buf, kt)                                                   \
  {                                                                         \
    _Pragma("unroll") for (int i = 0; i < 2; ++i) {                         \
      int idx = tid + i * 256;                                              \
      size_t go = (size_t)(brow + (idx >> 2)) * 1024 + (kt) * 32 + (idx & 3) * 8; \
      gload_lds16(Ahi + go, (char*)&lds[buf][0] + (wid * 64 + i * 256) * 16);     \
      gload_lds16(Alo + go, (char*)&lds[buf][4096] + (wid * 64 + i * 256) * 16);  \
    }                                                                       \
    _Pragma("unroll") for (int i = 0; i < 2; ++i) {                         \
      int idx = tid + i * 256;                                              \
      size_t go = (size_t)(bcol + (idx >> 2)) * 1024 + (kt) * 32 + (idx & 3) * 8; \
      gload_lds16(Bhi + go, (char*)&lds[buf][8192] + (wid * 64 + i * 256) * 16);  \
      gload_lds16(Blo + go, (char*)&lds[buf][12288] + (wid * 64 + i * 256) * 16); \
    }                                                                       \
  }

  STAGE_QK(0, 0);
  __syncthreads();
  int cur = 0;
  for (int kt = 0; kt < 32; ++kt) {
    if (kt + 1 < 32) STAGE_QK(cur ^ 1, kt + 1);
    const u16* LAh = &lds[cur][0];
    const u16* LAl = &lds[cur][4096];
    const u16* LBh = &lds[cur][8192];
    const u16* LBl = &lds[cur][12288];
    s16x8 ah[4], al[4], bh[4], bl[4];
#pragma unroll
    for (int ar = 0; ar < 4; ++ar) {
      int off = (wr * 64 + ar * 16 + lr) * 32 + lg * 8;
      ah[ar] = *(const s16x8*)(LAh + off);
      al[ar] = *(const s16x8*)(LAl + off);
    }
#pragma unroll
    for (int bc = 0; bc < 4; ++bc) {
      int off = (wc * 64 + bc * 16 + lr) * 32 + lg * 8;
      bh[bc] = *(const s16x8*)(LBh + off);
      bl[bc] = *(const s16x8*)(LBl + off);
    }
#pragma unroll
    for (int ar = 0; ar < 4; ++ar)
#pragma unroll
      for (int bc = 0; bc < 4; ++bc) {
        acc[ar][bc] = __builtin_amdgcn_mfma_f32_16x16x32_bf16(ah[ar], bh[bc], acc[ar][bc], 0, 0, 0);
        acc[ar][bc] = __builtin_amdgcn_mfma_f32_16x16x32_bf16(al[ar], bh[bc], acc[ar][bc], 0, 0, 0);
        acc[ar][bc] = __builtin_amdgcn_mfma_f32_16x16x32_bf16(ah[ar], bl[bc], acc[ar][bc], 0, 0, 0);
      }
    __syncthreads();
    cur ^= 1;
  }
#undef STAGE_QK

#pragma unroll
  for (int ar = 0; ar < 4; ++ar) {
    int row0 = brow + wr * 64 + ar * 16 + lg * 4;
    int bb = row0 >> 11, s0 = row0 & 2047;
#pragma unroll
    for (int bc = 0; bc < 4; ++bc) {
      int n = bcol + wc * 64 + bc * 16 + lr;
      int qk = n >> 10, hd = n & 1023, h = hd >> 6, d = hd & 63;
      float bias = (qk ? bk : bq)[hd];
      u16* Dhi = qk ? Khi : Qhi;
      u16* Dlo = qk ? Klo : Qlo;
      size_t base = ((size_t)(bb * NHEADS + h) * SEQ + s0) * DHEAD + d;
#pragma unroll
      for (int r = 0; r < 4; ++r) {
        float v = acc[ar][bc][r] + bias;
        u16 hh = f2bf(v);
        Dhi[base + (size_t)r * DHEAD] = hh;
        Dlo[base + (size_t)r * DHEAD] = f2bf(v - bf2f(hh));
      }
    }
  }
}

// ---------------- plain GEMM (V projection / out projection) ----------------
// EPI 0: V epilogue (bias + transpose-store Vt [bh][d][s] bf16), N=1024 (h*64+d)
// EPI 1: out epilogue (bias + fp32 store), N=1024
template <int EPI>
__global__ __launch_bounds__(256, 2) void gemm128(
    const u16* __restrict__ A, const u16* __restrict__ Bt,
    const float* __restrict__ bias_v, u16* __restrict__ Vto,
    const float* __restrict__ bo, float* __restrict__ Co) {
  __shared__ u16 lds[2][8192];
  const int tid = threadIdx.x;
  const int wid = tid >> 6, lane = tid & 63, lr = lane & 15, lg = lane >> 4;
  const int wr = wid >> 1, wc = wid & 1;
  const int brow = blockIdx.y * 128, bcol = blockIdx.x * 128;

  f32x4 acc[4][4];
#pragma unroll
  for (int i = 0; i < 4; ++i)
#pragma unroll
    for (int j = 0; j < 4; ++j) acc[i][j] = (f32x4){0.f, 0.f, 0.f, 0.f};

#define STAGE(buf, kt)                                                               \
  {                                                                                  \
    _Pragma("unroll") for (int i = 0; i < 2; ++i) {                                  \
      int idx = tid + i * 256;                                                       \
      gload_lds16(A + (size_t)(brow + (idx >> 2)) * 1024 + (kt) * 32 + (idx & 3) * 8,\
                  (char*)&lds[buf][0] + (wid * 64 + i * 256) * 16);                  \
    }                                                                                \
    _Pragma("unroll") for (int i = 0; i < 2; ++i) {                                  \
      int idx = tid + i * 256;                                                       \
      gload_lds16(Bt + (size_t)(bcol + (idx >> 2)) * 1024 + (kt) * 32 + (idx & 3) * 8,\
                  (char*)&lds[buf][4096] + (wid * 64 + i * 256) * 16);               \
    }                                                                                \
  }

  STAGE(0, 0);
  __syncthreads();
  int cur = 0;
  for (int kt = 0; kt < 32; ++kt) {
    if (kt + 1 < 32) STAGE(cur ^ 1, kt + 1);
    const u16* Ab = &lds[cur][0];
    const u16* Bb = &lds[cur][4096];
    s16x8 a[4], b[4];
#pragma unroll
    for (int ar = 0; ar < 4; ++ar)
      a[ar] = *(const s16x8*)(Ab + (wr * 64 + ar * 16 + lr) * 32 + lg * 8);
#pragma unroll
    for (int bc = 0; bc < 4; ++bc)
      b[bc] = *(const s16x8*)(Bb + (wc * 64 + bc * 16 + lr) * 32 + lg * 8);
#pragma unroll
    for (int ar = 0; ar < 4; ++ar)
#pragma unroll
      for (int bc = 0; bc < 4; ++bc)
        acc[ar][bc] = __builtin_amdgcn_mfma_f32_16x16x32_bf16(a[ar], b[bc], acc[ar][bc], 0, 0, 0);
    __syncthreads();
    cur ^= 1;
  }
#undef STAGE

#pragma unroll
  for (int ar = 0; ar < 4; ++ar) {
    int row0 = brow + wr * 64 + ar * 16 + lg * 4;
    int bb = row0 >> 11, s0 = row0 & 2047;
#pragma unroll
    for (int bc = 0; bc < 4; ++bc) {
      int n = bcol + wc * 64 + bc * 16 + lr;
      if (EPI == 0) {
        int h = n >> 6, d = n & 63;
        float bias = bias_v[n];
        u16x4 o;
        o[0] = f2bf(acc[ar][bc][0] + bias);
        o[1] = f2bf(acc[ar][bc][1] + bias);
        o[2] = f2bf(acc[ar][bc][2] + bias);
        o[3] = f2bf(acc[ar][bc][3] + bias);
        *(u16x4*)(Vto + ((size_t)(bb * NHEADS + h) * DHEAD + d) * SEQ + s0) = o;
      } else {
        float bias = bo[n];
#pragma unroll
        for (int r = 0; r < 4; ++r)
          Co[(size_t)(row0 + r) * DMODEL + n] = acc[ar][bc][r] + bias;
      }
    }
  }
}

// ---------------- flash attention (split-precision QK^T) ----------------
__global__ __launch_bounds__(256, 2) void attn_kernel(
    const u16* __restrict__ Qhi, const u16* __restrict__ Qlo,
    const u16* __restrict__ Khi, const u16* __restrict__ Klo,
    const u16* __restrict__ Vt, u16* __restrict__ MH) {
  __shared__ u16 qh_lds[4096], ql_lds[4096], kh_lds[4096], kl_lds[4096], v_lds[4096];
  __shared__ u16 p_lds[4][1024];
  const int tid = threadIdx.x, wid = tid >> 6, lane = tid & 63;
  const int lr = lane & 15, lg = lane >> 4;
  const int bid = blockIdx.x;
  const int bh = bid >> 5;
  const int qt = 31 - (bid & 31);        // heavy tiles first
  const int h = bh & 15, b = bh >> 4;
  const int q0 = qt * 64;
  const u16* Qhb = Qhi + (size_t)bh * (SEQ * DHEAD);
  const u16* Qlb = Qlo + (size_t)bh * (SEQ * DHEAD);
  const u16* Khb = Khi + (size_t)bh * (SEQ * DHEAD);
  const u16* Klb = Klo + (size_t)bh * (SEQ * DHEAD);
  const u16* Vb  = Vt  + (size_t)bh * (DHEAD * SEQ);

  // stage Q tiles [64][64] hi/lo, source pre-swizzled
#pragma unroll
  for (int i = 0; i < 2; ++i) {
    int idx = tid + i * 256;
    int row = idx >> 3, seg = idx & 7;
    int sseg = seg ^ (row & 7);
    gload_lds16(Qhb + (size_t)(q0 + row) * DHEAD + sseg * 8,
                (char*)qh_lds + (wid * 64 + i * 256) * 16);
    gload_lds16(Qlb + (size_t)(q0 + row) * DHEAD + sseg * 8,
                (char*)ql_lds + (wid * 64 + i * 256) * 16);
  }
  __syncthreads();

  s16x8 qfh[2], qfl[2];
#pragma unroll
  for (int ks = 0; ks < 2; ++ks) {
    int row = wid * 16 + lr;
    int off = (row * 128 + (ks * 4 + lg) * 16) ^ ((row & 7) << 4);
    qfh[ks] = *(const s16x8*)((const char*)qh_lds + off);
    qfl[ks] = *(const s16x8*)((const char*)ql_lds + off);
  }

  f32x4 acc_o[4];
#pragma unroll
  for (int db = 0; db < 4; ++db) acc_o[db] = (f32x4){0.f, 0.f, 0.f, 0.f};
  float mrow[4] = {-1e30f, -1e30f, -1e30f, -1e30f};
  float lrow[4] = {0.f, 0.f, 0.f, 0.f};
  const float sc = 0.18033688011112042f;   // (1/8) * log2(e)

  for (int kt = 0; kt <= qt; ++kt) {
    int k0 = kt * 64;
#pragma unroll
    for (int i = 0; i < 2; ++i) {
      int idx = tid + i * 256;
      int row = idx >> 3, seg = idx & 7;
      int sseg = seg ^ (row & 7);
      gload_lds16(Khb + (size_t)(k0 + row) * DHEAD + sseg * 8,
                  (char*)kh_lds + (wid * 64 + i * 256) * 16);
      gload_lds16(Klb + (size_t)(k0 + row) * DHEAD + sseg * 8,
                  (char*)kl_lds + (wid * 64 + i * 256) * 16);
      gload_lds16(Vb + (size_t)row * SEQ + k0 + sseg * 8,
                  (char*)v_lds + (wid * 64 + i * 256) * 16);
    }
    __syncthreads();

    // S = Q K^T, 3-term split
    f32x4 s4[4];
#pragma unroll
    for (int cb = 0; cb < 4; ++cb) s4[cb] = (f32x4){0.f, 0.f, 0.f, 0.f};
#pragma unroll
    for (int ks = 0; ks < 2; ++ks)
#pragma unroll
      for (int cb = 0; cb < 4; ++cb) {
        int row = cb * 16 + lr;
        int off = (row * 128 + (ks * 4 + lg) * 16) ^ ((row & 7) << 4);
        s16x8 kbh = *(const s16x8*)((const char*)kh_lds + off);
        s16x8 kbl = *(const s16x8*)((const char*)kl_lds + off);
        s4[cb] = __builtin_amdgcn_mfma_f32_16x16x32_bf16(qfh[ks], kbh, s4[cb], 0, 0, 0);
        s4[cb] = __builtin_amdgcn_mfma_f32_16x16x32_bf16(qfl[ks], kbh, s4[cb], 0, 0, 0);
        s4[cb] = __builtin_amdgcn_mfma_f32_16x16x32_bf16(qfh[ks], kbl, s4[cb], 0, 0, 0);
      }

    const bool diag = (kt == qt);
    float t[4][4];
#pragma unroll
    for (int cb = 0; cb < 4; ++cb)
#pragma unroll
      for (int r = 0; r < 4; ++r) {
        float v = s4[cb][r] * sc;
        if (diag) {
          int kcol = k0 + cb * 16 + lr;
          int qrow = q0 + wid * 16 + lg * 4 + r;
          if (kcol > qrow) v = -1e30f;
        }
        t[cb][r] = v;
      }

    float alpha[4];
#pragma unroll
    for (int r = 0; r < 4; ++r) {
      float tm = fmaxf(fmaxf(t[0][r], t[1][r]), fmaxf(t[2][r], t[3][r]));
      tm = fmaxf(tm, __shfl_xor(tm, 1));
      tm = fmaxf(tm, __shfl_xor(tm, 2));
      tm = fmaxf(tm, __shfl_xor(tm, 4));
      tm = fmaxf(tm, __shfl_xor(tm, 8));
      float m2 = fmaxf(mrow[r], tm);
      alpha[r] = exp2f(mrow[r] - m2);
      mrow[r] = m2;
    }

    float rs[4] = {0.f, 0.f, 0.f, 0.f};
    u16 pb[4][4];
#pragma unroll
    for (int cb = 0; cb < 4; ++cb)
#pragma unroll
      for (int r = 0; r < 4; ++r) {
        float p = exp2f(t[cb][r] - mrow[r]);
        rs[r] += p;
        pb[cb][r] = f2bf(p);
      }
#pragma unroll
    for (int r = 0; r < 4; ++r) {
      float s = rs[r];
      s += __shfl_xor(s, 1);
      s += __shfl_xor(s, 2);
      s += __shfl_xor(s, 4);
      s += __shfl_xor(s, 8);
      lrow[r] = lrow[r] * alpha[r] + s;
#pragma unroll
      for (int db = 0; db < 4; ++db) acc_o[db][r] *= alpha[r];
    }

    u16* pw = p_lds[wid];
#pragma unroll
    for (int cb = 0; cb < 4; ++cb)
#pragma unroll
      for (int r = 0; r < 4; ++r) {
        int row = lg * 4 + r, col = cb * 16 + lr;
        *(u16*)((char*)pw + ((row * 128 + col * 2) ^ ((row & 7) << 4))) = pb[cb][r];
      }

#pragma unroll
    for (int ks = 0; ks < 2; ++ks) {
      s16x8 pa = *(const s16x8*)((const char*)pw +
                                 ((lr * 128 + (ks * 4 + lg) * 16) ^ ((lr & 7) << 4)));
#pragma unroll
      for (int db = 0; db < 4; ++db) {
        int row = db * 16 + lr;
        s16x8 vb = *(const s16x8*)((const char*)v_lds +
                                   ((row * 128 + (ks * 4 + lg) * 16) ^ ((row & 7) << 4)));
        acc_o[db] = __builtin_amdgcn_mfma_f32_16x16x32_bf16(pa, vb, acc_o[db], 0, 0, 0);
      }
    }
    __syncthreads();
  }

#pragma unroll
  for (int db = 0; db < 4; ++db)
#pragma unroll
    for (int r = 0; r < 4; ++r) {
      int qrow = q0 + wid * 16 + lg * 4 + r;
      float v = acc_o[db][r] / lrow[r];
      MH[((size_t)(b * SEQ + qrow)) * DMODEL + h * DHEAD + db * 16 + lr] = f2bf(v);
    }
}

// ---------------- launcher ----------------
extern "C" void kernel_launch(void* const* d_in, const int* in_sizes, int n_in,
                              void* d_out, int out_size, void* d_ws, size_t ws_size,
                              hipStream_t stream) {
  const float* residual = (const float*)d_in[0];
  const float* WQ = (const float*)d_in[1];
  const float* WK = (const float*)d_in[2];
  const float* WV = (const float*)d_in[3];
  const float* WO = (const float*)d_in[4];
  const float* bQ = (const float*)d_in[5];
  const float* bK = (const float*)d_in[6];
  const float* bV = (const float*)d_in[7];
  const float* bO = (const float*)d_in[8];
  float* out = (float*)d_out;

  char* w = (char*)d_ws;
  u16* Xhi = (u16*)(w);                        // 8 MB  [4096][1024]
  u16* Xlo = (u16*)(w + ((size_t)8 << 20));    // 8 MB
  u16* Whi = (u16*)(w + ((size_t)16 << 20));   // 6 MB  [3072][1024]
  u16* Wlo = (u16*)(w + ((size_t)22 << 20));   // 6 MB
  u16* Wo  = (u16*)(w + ((size_t)28 << 20));   // 2 MB  [1024][1024]
  u16* Qhi = (u16*)(w + ((size_t)30 << 20));   // 8 MB  [32][2048][64]
  u16* Qlo = (u16*)(w + ((size_t)38 << 20));   // 8 MB
  u16* Khi = (u16*)(w + ((size_t)46 << 20));   // 8 MB
  u16* Klo = (u16*)(w + ((size_t)54 << 20));   // 8 MB
  u16* Vtd = (u16*)(w + ((size_t)62 << 20));   // 8 MB  [32][64][2048]
  u16* MH  = (u16*)(w + ((size_t)8 << 20));    // aliases Xlo (dead after gemm_qk)

  pack_x_kernel<<<2048, 256, 0, stream>>>(residual, Xhi, Xlo);
  pack_wqkv_kernel<<<3072, 256, 0, stream>>>(WQ, WK, WV, Whi, Wlo);
  pack_wo_kernel<<<1024, 256, 0, stream>>>(WO, Wo);

  gemm_qk<<<dim3(NQK / 128, MROWS / 128), 256, 0, stream>>>(
      Xhi, Xlo, Whi, Wlo, bQ, bK, Qhi, Qlo, Khi, Klo);

  gemm128<0><<<dim3(DMODEL / 128, MROWS / 128), 256, 0, stream>>>(
      Xhi, Whi + (size_t)NQK * DMODEL, bV, Vtd, nullptr, nullptr);

  attn_kernel<<<NBATCH * NHEADS * 32, 256, 0, stream>>>(Qhi, Qlo, Khi, Klo, Vtd, MH);

  gemm128<1><<<dim3(DMODEL / 128, MROWS / 128), 256, 0, stream>>>(
      MH, Wo, nullptr, nullptr, bO, out);
}

// Round 3
// 220.119 us; speedup vs baseline: 1.2985x; 1.2985x over previous
//
#include <hip/hip_runtime.h>
#include <stdint.h>

typedef unsigned short u16;
typedef __attribute__((ext_vector_type(8))) short s16x8;   // 8 bf16 MFMA frag
typedef __attribute__((ext_vector_type(4))) float f32x4;   // MFMA accumulator
typedef __attribute__((ext_vector_type(4))) unsigned short u16x4;
typedef __attribute__((ext_vector_type(8))) unsigned short u16x8;

#define NHEADS 16
#define DMODEL 1024
#define DHEAD 64
#define SEQ 2048
#define NBATCH 2
#define MROWS (NBATCH * SEQ)   /* 4096 */
#define NQK 2048               /* Q,K output cols */

__device__ __forceinline__ u16 f2bf(float x) {
  union { float f; unsigned u; } v; v.f = x;
  return (u16)((v.u + 0x7fffu + ((v.u >> 16) & 1u)) >> 16);  // RNE
}
__device__ __forceinline__ float bf2f(u16 h) {
  union { unsigned u; float f; } v; v.u = ((unsigned)h) << 16; return v.f;
}

__device__ __forceinline__ void gload_lds16(const void* g, void* l) {
  __builtin_amdgcn_global_load_lds(
      (const __attribute__((address_space(1))) void*)g,
      (__attribute__((address_space(3))) void*)l, 16, 0, 0);
}

// ---------------- prep kernels ----------------

__global__ __launch_bounds__(256) void pack_x_kernel(const float* __restrict__ X,
                                                     u16* __restrict__ Xhi,
                                                     u16* __restrict__ Xlo) {
  int i = blockIdx.x * 256 + threadIdx.x;
  const f32x4* xv = (const f32x4*)(X + (size_t)i * 8);
  f32x4 a = xv[0], b = xv[1];
  float vals[8] = {a[0], a[1], a[2], a[3], b[0], b[1], b[2], b[3]};
  u16x8 oh, ol;
#pragma unroll
  for (int j = 0; j < 8; ++j) {
    u16 h = f2bf(vals[j]);
    oh[j] = h;
    ol[j] = f2bf(vals[j] - bf2f(h));
  }
  *(u16x8*)(Xhi + (size_t)i * 8) = oh;
  *(u16x8*)(Xlo + (size_t)i * 8) = ol;
}

__global__ __launch_bounds__(256) void pack_wqkv_kernel(const float* __restrict__ WQ,
                                                        const float* __restrict__ WK,
                                                        const float* __restrict__ WV,
                                                        u16* __restrict__ Whi,
                                                        u16* __restrict__ Wlo) {
  int n = blockIdx.x;                                // 3072 blocks
  int qkv = n >> 10, hd = n & 1023, h = hd >> 6, d = hd & 63;
  const float* W = (qkv == 0) ? WQ : ((qkv == 1) ? WK : WV);
  const float* src = W + (size_t)h * DMODEL * DHEAD + d;
  int m0 = threadIdx.x * 4;
  u16x4 oh, ol;
#pragma unroll
  for (int j = 0; j < 4; ++j) {
    float v = src[(size_t)(m0 + j) * DHEAD];
    u16 hh = f2bf(v);
    oh[j] = hh;
    ol[j] = f2bf(v - bf2f(hh));
  }
  *(u16x4*)(Whi + (size_t)n * DMODEL + m0) = oh;
  *(u16x4*)(Wlo + (size_t)n * DMODEL + m0) = ol;
}

__global__ __launch_bounds__(256) void pack_wo_kernel(const float* __restrict__ WO,
                                                      u16* __restrict__ Wt) {
  int m = blockIdx.x;
  int e0 = threadIdx.x * 4;
  u16x4 o;
#pragma unroll
  for (int j = 0; j < 4; ++j) o[j] = f2bf(WO[(size_t)(e0 + j) * DMODEL + m]);
  *(u16x4*)(Wt + (size_t)m * DMODEL + e0) = o;
}

// ---------------- split-precision GEMM for Q,K ----------------
__global__ __launch_bounds__(256, 2) void gemm_qk(
    const u16* __restrict__ Ahi, const u16* __restrict__ Alo,
    const u16* __restrict__ Bhi, const u16* __restrict__ Blo,
    const float* __restrict__ bq, const float* __restrict__ bk,
    u16* __restrict__ Qhi, u16* __restrict__ Qlo,
    u16* __restrict__ Khi, u16* __restrict__ Klo) {
  __shared__ u16 lds[2][16384];  // [buf][Ahi|Alo|Bhi|Blo] 4096 u16 each
  const int tid = threadIdx.x;
  const int wid = tid >> 6, lane = tid & 63, lr = lane & 15, lg = lane >> 4;
  const int wr = wid >> 1, wc = wid & 1;
  const int brow = blockIdx.y * 128, bcol = blockIdx.x * 128;

  f32x4 acc[4][4];
#pragma unroll
  for (int i = 0; i < 4; ++i)
#pragma unroll
    for (int j = 0; j < 4; ++j) acc[i][j] = (f32x4){0.f, 0.f, 0.f, 0.f};

#define STAGE_QK(buf, kt)                                                   \
  {                                                                         \
    _Pragma("unroll") for (int i = 0; i < 2; ++i) {                         \
      int idx = tid + i * 256;                                              \
      size_t go = (size_t)(brow + (idx >> 2)) * 1024 + (kt) * 32 + (idx & 3) * 8; \
      gload_lds16(Ahi + go, (char*)&lds[buf][0] + (wid * 64 + i * 256) * 16);     \
      gload_lds16(Alo + go, (char*)&lds[buf][4096] + (wid * 64 + i * 256) * 16);  \
    }                                                                       \
    _Pragma("unroll") for (int i = 0; i < 2; ++i) {                         \
      int idx = tid + i * 256;                                              \
      size_t go = (size_t)(bcol + (idx >> 2)) * 1024 + (kt) * 32 + (idx & 3) * 8; \
      gload_lds16(Bhi + go, (char*)&lds[buf][8192] + (wid * 64 + i * 256) * 16);  \
      gload_lds16(Blo + go, (char*)&lds[buf][12288] + (wid * 64 + i * 256) * 16); \
    }                                                                       \
  }

  STAGE_QK(0, 0);
  __syncthreads();
  int cur = 0;
  for (int kt = 0; kt < 32; ++kt) {
    if (kt + 1 < 32) STAGE_QK(cur ^ 1, kt + 1);
    const u16* LAh = &lds[cur][0];
    const u16* LAl = &lds[cur][4096];
    const u16* LBh = &lds[cur][8192];
    const u16* LBl = &lds[cur][12288];
    s16x8 ah[4], al[4], bh[4], bl[4];
#pragma unroll
    for (int ar = 0; ar < 4; ++ar) {
      int off = (wr * 64 + ar * 16 + lr) * 32 + lg * 8;
      ah[ar] = *(const s16x8*)(LAh + off);
      al[ar] = *(const s16x8*)(LAl + off);
    }
#pragma unroll
    for (int bc = 0; bc < 4; ++bc) {
      int off = (wc * 64 + bc * 16 + lr) * 32 + lg * 8;
      bh[bc] = *(const s16x8*)(LBh + off);
      bl[bc] = *(const s16x8*)(LBl + off);
    }
#pragma unroll
    for (int ar = 0; ar < 4; ++ar)
#pragma unroll
      for (int bc = 0; bc < 4; ++bc) {
        acc[ar][bc] = __builtin_amdgcn_mfma_f32_16x16x32_bf16(ah[ar], bh[bc], acc[ar][bc], 0, 0, 0);
        acc[ar][bc] = __builtin_amdgcn_mfma_f32_16x16x32_bf16(al[ar], bh[bc], acc[ar][bc], 0, 0, 0);
        acc[ar][bc] = __builtin_amdgcn_mfma_f32_16x16x32_bf16(ah[ar], bl[bc], acc[ar][bc], 0, 0, 0);
      }
    __syncthreads();
    cur ^= 1;
  }
#undef STAGE_QK

#pragma unroll
  for (int ar = 0; ar < 4; ++ar) {
    int row0 = brow + wr * 64 + ar * 16 + lg * 4;
    int bb = row0 >> 11, s0 = row0 & 2047;
#pragma unroll
    for (int bc = 0; bc < 4; ++bc) {
      int n = bcol + wc * 64 + bc * 16 + lr;
      int qk = n >> 10, hd = n & 1023, h = hd >> 6, d = hd & 63;
      float bias = (qk ? bk : bq)[hd];
      u16* Dhi = qk ? Khi : Qhi;
      u16* Dlo = qk ? Klo : Qlo;
      size_t base = ((size_t)(bb * NHEADS + h) * SEQ + s0) * DHEAD + d;
#pragma unroll
      for (int r = 0; r < 4; ++r) {
        float v = acc[ar][bc][r] + bias;
        u16 hh = f2bf(v);
        Dhi[base + (size_t)r * DHEAD] = hh;
        Dlo[base + (size_t)r * DHEAD] = f2bf(v - bf2f(hh));
      }
    }
  }
}

// ---------------- plain GEMM (V projection / out projection) ----------------
template <int EPI>
__global__ __launch_bounds__(256, 2) void gemm128(
    const u16* __restrict__ A, const u16* __restrict__ Bt,
    const float* __restrict__ bias_v, u16* __restrict__ Vto,
    const float* __restrict__ bo, float* __restrict__ Co) {
  __shared__ u16 lds[2][8192];
  const int tid = threadIdx.x;
  const int wid = tid >> 6, lane = tid & 63, lr = lane & 15, lg = lane >> 4;
  const int wr = wid >> 1, wc = wid & 1;
  const int brow = blockIdx.y * 128, bcol = blockIdx.x * 128;

  f32x4 acc[4][4];
#pragma unroll
  for (int i = 0; i < 4; ++i)
#pragma unroll
    for (int j = 0; j < 4; ++j) acc[i][j] = (f32x4){0.f, 0.f, 0.f, 0.f};

#define STAGE(buf, kt)                                                               \
  {                                                                                  \
    _Pragma("unroll") for (int i = 0; i < 2; ++i) {                                  \
      int idx = tid + i * 256;                                                       \
      gload_lds16(A + (size_t)(brow + (idx >> 2)) * 1024 + (kt) * 32 + (idx & 3) * 8,\
                  (char*)&lds[buf][0] + (wid * 64 + i * 256) * 16);                  \
    }                                                                                \
    _Pragma("unroll") for (int i = 0; i < 2; ++i) {                                  \
      int idx = tid + i * 256;                                                       \
      gload_lds16(Bt + (size_t)(bcol + (idx >> 2)) * 1024 + (kt) * 32 + (idx & 3) * 8,\
                  (char*)&lds[buf][4096] + (wid * 64 + i * 256) * 16);               \
    }                                                                                \
  }

  STAGE(0, 0);
  __syncthreads();
  int cur = 0;
  for (int kt = 0; kt < 32; ++kt) {
    if (kt + 1 < 32) STAGE(cur ^ 1, kt + 1);
    const u16* Ab = &lds[cur][0];
    const u16* Bb = &lds[cur][4096];
    s16x8 a[4], b[4];
#pragma unroll
    for (int ar = 0; ar < 4; ++ar)
      a[ar] = *(const s16x8*)(Ab + (wr * 64 + ar * 16 + lr) * 32 + lg * 8);
#pragma unroll
    for (int bc = 0; bc < 4; ++bc)
      b[bc] = *(const s16x8*)(Bb + (wc * 64 + bc * 16 + lr) * 32 + lg * 8);
#pragma unroll
    for (int ar = 0; ar < 4; ++ar)
#pragma unroll
      for (int bc = 0; bc < 4; ++bc)
        acc[ar][bc] = __builtin_amdgcn_mfma_f32_16x16x32_bf16(a[ar], b[bc], acc[ar][bc], 0, 0, 0);
    __syncthreads();
    cur ^= 1;
  }
#undef STAGE

#pragma unroll
  for (int ar = 0; ar < 4; ++ar) {
    int row0 = brow + wr * 64 + ar * 16 + lg * 4;
    int bb = row0 >> 11, s0 = row0 & 2047;
#pragma unroll
    for (int bc = 0; bc < 4; ++bc) {
      int n = bcol + wc * 64 + bc * 16 + lr;
      if (EPI == 0) {
        int h = n >> 6, d = n & 63;
        float bias = bias_v[n];
        u16x4 o;
        o[0] = f2bf(acc[ar][bc][0] + bias);
        o[1] = f2bf(acc[ar][bc][1] + bias);
        o[2] = f2bf(acc[ar][bc][2] + bias);
        o[3] = f2bf(acc[ar][bc][3] + bias);
        *(u16x4*)(Vto + ((size_t)(bb * NHEADS + h) * DHEAD + d) * SEQ + s0) = o;
      } else {
        float bias = bo[n];
#pragma unroll
        for (int r = 0; r < 4; ++r)
          Co[(size_t)(row0 + r) * DMODEL + n] = acc[ar][bc][r] + bias;
      }
    }
  }
}

// ---------------- flash attention: paired q-tiles + double-buffered K/V ----------------
// grid: 512 blocks = pair p (0..15) x bh (0..31). Block handles q-tiles {31-p, p}
// -> every block does exactly 33 k-iterations (perfect balance), all 512 resident (2/CU).
// LDS 56KB: buf0 [Khi|Klo|V] 24KB, buf1 24KB, P 8KB (wave-private 2KB).
// Q (both tiles, hi+lo) staged once into buf1+P regions, moved to regs, regions reused.
__global__ __launch_bounds__(256, 2) void attn_kernel(
    const u16* __restrict__ Qhi, const u16* __restrict__ Qlo,
    const u16* __restrict__ Khi, const u16* __restrict__ Klo,
    const u16* __restrict__ Vt, u16* __restrict__ MH) {
  __shared__ u16 sh[28672];   // 56 KB
  const int tid = threadIdx.x, wid = tid >> 6, lane = tid & 63;
  const int lr = lane & 15, lg = lane >> 4;
  const int bid = blockIdx.x;
  const int p = bid >> 5;          // pair index, heavy pairs dispatched first
  const int bh = bid & 31;
  const int h = bh & 15, b = bh >> 4;
  const int tA = 31 - p, tB = p;
  const u16* Qhb = Qhi + (size_t)bh * (SEQ * DHEAD);
  const u16* Qlb = Qlo + (size_t)bh * (SEQ * DHEAD);
  const u16* Khb = Khi + (size_t)bh * (SEQ * DHEAD);
  const u16* Klb = Klo + (size_t)bh * (SEQ * DHEAD);
  const u16* Vb  = Vt  + (size_t)bh * (DHEAD * SEQ);

#define ASTAGE(bufbyte, kt)                                                        \
  { _Pragma("unroll") for (int i = 0; i < 2; ++i) {                                \
      int idx = tid + i * 256;                                                     \
      int row = idx >> 3, sseg = (idx & 7) ^ (row & 7);                            \
      size_t koff = (size_t)((kt) * 64 + row) * DHEAD + sseg * 8;                  \
      char* dst = (char*)sh + (bufbyte) + (wid * 64 + i * 256) * 16;               \
      gload_lds16(Khb + koff, dst);                                                \
      gload_lds16(Klb + koff, dst + 8192);                                         \
      gload_lds16(Vb + (size_t)row * SEQ + (kt) * 64 + sseg * 8, dst + 16384);     \
  } }

  // ---- prologue: stage Q for both tiles (QA_hi@24576 QA_lo@32768 QB_hi@40960 QB_lo@49152) ----
#pragma unroll
  for (int i = 0; i < 2; ++i) {
    int idx = tid + i * 256;
    int row = idx >> 3, sseg = (idx & 7) ^ (row & 7);
    size_t offA = (size_t)(tA * 64 + row) * DHEAD + sseg * 8;
    size_t offB = (size_t)(tB * 64 + row) * DHEAD + sseg * 8;
    char* d = (char*)sh + (wid * 64 + i * 256) * 16;
    gload_lds16(Qhb + offA, d + 24576);
    gload_lds16(Qlb + offA, d + 32768);
    gload_lds16(Qhb + offB, d + 40960);
    gload_lds16(Qlb + offB, d + 49152);
  }
  ASTAGE(0, 0);
  __syncthreads();

  s16x8 qfh[2][2], qfl[2][2];
#pragma unroll
  for (int seg = 0; seg < 2; ++seg)
#pragma unroll
    for (int ks = 0; ks < 2; ++ks) {
      int row = wid * 16 + lr;
      int off = (row * 128 + (ks * 4 + lg) * 16) ^ ((row & 7) << 4);
      qfh[seg][ks] = *(const s16x8*)((const char*)sh + (seg ? 40960 : 24576) + off);
      qfl[seg][ks] = *(const s16x8*)((const char*)sh + (seg ? 49152 : 32768) + off);
    }
  __syncthreads();   // all waves done reading Q before buf1/P regions are reused

  const float sc = 0.18033688011112042f;   // (1/8) * log2(e)
  int cur = 0;

#pragma unroll
  for (int seg = 0; seg < 2; ++seg) {
    const int t = seg ? tB : tA;
    const int q0 = t * 64;
    f32x4 acc_o[4];
    float mrow[4], lrow[4];
#pragma unroll
    for (int z = 0; z < 4; ++z) {
      acc_o[z] = (f32x4){0.f, 0.f, 0.f, 0.f};
      mrow[z] = -1e30f;
      lrow[z] = 0.f;
    }

    for (int kt = 0; kt <= t; ++kt) {
      int nxt = (kt < t) ? kt + 1 : ((seg == 0) ? 0 : -1);
      if (nxt >= 0) ASTAGE((cur ^ 1) * 24576, nxt);

      const char* kb = (const char*)sh + cur * 24576;
      f32x4 s4[4];
#pragma unroll
      for (int cb = 0; cb < 4; ++cb) s4[cb] = (f32x4){0.f, 0.f, 0.f, 0.f};
#pragma unroll
      for (int ks = 0; ks < 2; ++ks)
#pragma unroll
        for (int cb = 0; cb < 4; ++cb) {
          int row = cb * 16 + lr;
          int off = (row * 128 + (ks * 4 + lg) * 16) ^ ((row & 7) << 4);
          s16x8 kbh = *(const s16x8*)(kb + off);
          s16x8 kbl = *(const s16x8*)(kb + 8192 + off);
          s4[cb] = __builtin_amdgcn_mfma_f32_16x16x32_bf16(qfh[seg][ks], kbh, s4[cb], 0, 0, 0);
          s4[cb] = __builtin_amdgcn_mfma_f32_16x16x32_bf16(qfl[seg][ks], kbh, s4[cb], 0, 0, 0);
          s4[cb] = __builtin_amdgcn_mfma_f32_16x16x32_bf16(qfh[seg][ks], kbl, s4[cb], 0, 0, 0);
        }

      const bool diag = (kt == t);
      float tv[4][4];
#pragma unroll
      for (int cb = 0; cb < 4; ++cb)
#pragma unroll
        for (int r = 0; r < 4; ++r) {
          float v = s4[cb][r] * sc;
          if (diag && (cb * 16 + lr > wid * 16 + lg * 4 + r)) v = -1e30f;
          tv[cb][r] = v;
        }

      float alpha[4];
#pragma unroll
      for (int r = 0; r < 4; ++r) {
        float tm = fmaxf(fmaxf(tv[0][r], tv[1][r]), fmaxf(tv[2][r], tv[3][r]));
        tm = fmaxf(tm, __shfl_xor(tm, 1));
        tm = fmaxf(tm, __shfl_xor(tm, 2));
        tm = fmaxf(tm, __shfl_xor(tm, 4));
        tm = fmaxf(tm, __shfl_xor(tm, 8));
        float m2 = fmaxf(mrow[r], tm);
        alpha[r] = exp2f(mrow[r] - m2);
        mrow[r] = m2;
      }

      float rs[4] = {0.f, 0.f, 0.f, 0.f};
      u16 pb[4][4];
#pragma unroll
      for (int cb = 0; cb < 4; ++cb)
#pragma unroll
        for (int r = 0; r < 4; ++r) {
          float pv = exp2f(tv[cb][r] - mrow[r]);
          rs[r] += pv;
          pb[cb][r] = f2bf(pv);
        }
#pragma unroll
      for (int r = 0; r < 4; ++r) {
        float s = rs[r];
        s += __shfl_xor(s, 1);
        s += __shfl_xor(s, 2);
        s += __shfl_xor(s, 4);
        s += __shfl_xor(s, 8);
        lrow[r] = lrow[r] * alpha[r] + s;
#pragma unroll
        for (int db = 0; db < 4; ++db) acc_o[db][r] *= alpha[r];
      }

      char* pw = (char*)sh + 49152 + wid * 2048;
#pragma unroll
      for (int cb = 0; cb < 4; ++cb)
#pragma unroll
        for (int r = 0; r < 4; ++r) {
          int row = lg * 4 + r, col = cb * 16 + lr;
          *(u16*)(pw + ((row * 128 + col * 2) ^ ((row & 7) << 4))) = pb[cb][r];
        }

#pragma unroll
      for (int ks = 0; ks < 2; ++ks) {
        s16x8 pa = *(const s16x8*)(pw + ((lr * 128 + (ks * 4 + lg) * 16) ^ ((lr & 7) << 4)));
#pragma unroll
        for (int db = 0; db < 4; ++db) {
          int row = db * 16 + lr;
          s16x8 vb = *(const s16x8*)(kb + 16384 +
                                     ((row * 128 + (ks * 4 + lg) * 16) ^ ((row & 7) << 4)));
          acc_o[db] = __builtin_amdgcn_mfma_f32_16x16x32_bf16(pa, vb, acc_o[db], 0, 0, 0);
        }
      }
      __syncthreads();   // drains prefetch vmcnt + guards buffer swap
      cur ^= 1;
    }

    // store this tile's output
#pragma unroll
    for (int db = 0; db < 4; ++db)
#pragma unroll
      for (int r = 0; r < 4; ++r) {
        int qrow = q0 + wid * 16 + lg * 4 + r;
        MH[((size_t)(b * SEQ + qrow)) * DMODEL + h * DHEAD + db * 16 + lr] =
            f2bf(acc_o[db][r] / lrow[r]);
      }
  }
#undef ASTAGE
}

// ---------------- launcher ----------------
extern "C" void kernel_launch(void* const* d_in, const int* in_sizes, int n_in,
                              void* d_out, int out_size, void* d_ws, size_t ws_size,
                              hipStream_t stream) {
  const float* residual = (const float*)d_in[0];
  const float* WQ = (const float*)d_in[1];
  const float* WK = (const float*)d_in[2];
  const float* WV = (const float*)d_in[3];
  const float* WO = (const float*)d_in[4];
  const float* bQ = (const float*)d_in[5];
  const float* bK = (const float*)d_in[6];
  const float* bV = (const float*)d_in[7];
  const float* bO = (const float*)d_in[8];
  float* out = (float*)d_out;

  char* w = (char*)d_ws;
  u16* Xhi = (u16*)(w);                        // 8 MB  [4096][1024]
  u16* Xlo = (u16*)(w + ((size_t)8 << 20));    // 8 MB
  u16* Whi = (u16*)(w + ((size_t)16 << 20));   // 6 MB  [3072][1024]
  u16* Wlo = (u16*)(w + ((size_t)22 << 20));   // 6 MB
  u16* Wo  = (u16*)(w + ((size_t)28 << 20));   // 2 MB  [1024][1024]
  u16* Qhi = (u16*)(w + ((size_t)30 << 20));   // 8 MB  [32][2048][64]
  u16* Qlo = (u16*)(w + ((size_t)38 << 20));   // 8 MB
  u16* Khi = (u16*)(w + ((size_t)46 << 20));   // 8 MB
  u16* Klo = (u16*)(w + ((size_t)54 << 20));   // 8 MB
  u16* Vtd = (u16*)(w + ((size_t)62 << 20));   // 8 MB  [32][64][2048]
  u16* MH  = (u16*)(w + ((size_t)8 << 20));    // aliases Xlo (dead after gemm_qk)

  pack_x_kernel<<<2048, 256, 0, stream>>>(residual, Xhi, Xlo);
  pack_wqkv_kernel<<<3072, 256, 0, stream>>>(WQ, WK, WV, Whi, Wlo);
  pack_wo_kernel<<<1024, 256, 0, stream>>>(WO, Wo);

  gemm_qk<<<dim3(NQK / 128, MROWS / 128), 256, 0, stream>>>(
      Xhi, Xlo, Whi, Wlo, bQ, bK, Qhi, Qlo, Khi, Klo);

  gemm128<0><<<dim3(DMODEL / 128, MROWS / 128), 256, 0, stream>>>(
      Xhi, Whi + (size_t)NQK * DMODEL, bV, Vtd, nullptr, nullptr);

  attn_kernel<<<512, 256, 0, stream>>>(Qhi, Qlo, Khi, Klo, Vtd, MH);

  gemm128<1><<<dim3(DMODEL / 128, MROWS / 128), 256, 0, stream>>>(
      MH, Wo, nullptr, nullptr, bO, out);
}

// Round 4
// 176.621 us; speedup vs baseline: 1.6183x; 1.2463x over previous
//
#include <hip/hip_runtime.h>
#include <stdint.h>

typedef unsigned short u16;
typedef __attribute__((ext_vector_type(8))) short s16x8;   // 8 bf16 MFMA frag
typedef __attribute__((ext_vector_type(4))) float f32x4;   // MFMA accumulator
typedef __attribute__((ext_vector_type(4))) unsigned short u16x4;
typedef __attribute__((ext_vector_type(8))) unsigned short u16x8;
typedef __attribute__((ext_vector_type(2))) unsigned u32x2;

#define NHEADS 16
#define DMODEL 1024
#define DHEAD 64
#define SEQ 2048
#define NBATCH 2
#define MROWS (NBATCH * SEQ)   /* 4096 */
#define NQK 2048               /* Q,K output cols */
#define SCQ 0.18033688011112042f   /* (1/8) * log2(e), folded into Q */

__device__ __forceinline__ u16 f2bf(float x) {
  union { float f; unsigned u; } v; v.f = x;
  return (u16)((v.u + 0x7fffu + ((v.u >> 16) & 1u)) >> 16);  // RNE
}
__device__ __forceinline__ float bf2f(u16 h) {
  union { unsigned u; float f; } v; v.u = ((unsigned)h) << 16; return v.f;
}

__device__ __forceinline__ void gload_lds16(const void* g, void* l) {
  __builtin_amdgcn_global_load_lds(
      (const __attribute__((address_space(1))) void*)g,
      (__attribute__((address_space(3))) void*)l, 16, 0, 0);
}

// ---------------- prep kernels ----------------

// residual fp32 -> bf16 hi/lo planes, 8 elems/thread
__global__ __launch_bounds__(256) void pack_x_kernel(const float* __restrict__ X,
                                                     u16* __restrict__ Xhi,
                                                     u16* __restrict__ Xlo) {
  int i = blockIdx.x * 256 + threadIdx.x;
  const f32x4* xv = (const f32x4*)(X + (size_t)i * 8);
  f32x4 a = xv[0], b = xv[1];
  float vals[8] = {a[0], a[1], a[2], a[3], b[0], b[1], b[2], b[3]};
  u16x8 oh, ol;
#pragma unroll
  for (int j = 0; j < 8; ++j) {
    u16 h = f2bf(vals[j]);
    oh[j] = h;
    ol[j] = f2bf(vals[j] - bf2f(h));
  }
  *(u16x8*)(Xhi + (size_t)i * 8) = oh;
  *(u16x8*)(Xlo + (size_t)i * 8) = ol;
}

// W_{Q,K,V}[h][m][d] fp32 -> Wt[n][m] hi/lo via LDS transpose, coalesced.
// grid 768 = qkv(3) x h(16) x mtile(16); block 256.
__global__ __launch_bounds__(256) void pack_wqkv_t(const float* __restrict__ WQ,
                                                   const float* __restrict__ WK,
                                                   const float* __restrict__ WV,
                                                   u16* __restrict__ Whi,
                                                   u16* __restrict__ Wlo) {
  __shared__ u16 lh[64][72];
  __shared__ u16 ll[64][72];
  int blk = blockIdx.x;
  int mt = blk & 15, hh = (blk >> 4) & 15, qkv = blk >> 8;
  const float* W = (qkv == 0) ? WQ : (qkv == 1) ? WK : WV;
  int m_in = threadIdx.x >> 2, dq = threadIdx.x & 3;
  const f32x4* sp4 = (const f32x4*)(W + (size_t)hh * (DMODEL * DHEAD) +
                                    (size_t)(mt * 64 + m_in) * DHEAD + dq * 16);
#pragma unroll
  for (int v4 = 0; v4 < 4; ++v4) {
    f32x4 a = sp4[v4];
#pragma unroll
    for (int j = 0; j < 4; ++j) {
      float v = a[j];
      u16 hb = f2bf(v);
      int d = dq * 16 + v4 * 4 + j;
      lh[d][m_in] = hb;
      ll[d][m_in] = f2bf(v - bf2f(hb));
    }
  }
  __syncthreads();
  int d_in = threadIdx.x >> 2, mq = threadIdx.x & 3;
  size_t orow = ((size_t)(qkv * 1024 + hh * 64 + d_in)) * DMODEL + mt * 64 + mq * 16;
  u16x8 oh0, oh1, ol0, ol1;
#pragma unroll
  for (int j = 0; j < 8; ++j) {
    oh0[j] = lh[d_in][mq * 16 + j];
    oh1[j] = lh[d_in][mq * 16 + 8 + j];
    ol0[j] = ll[d_in][mq * 16 + j];
    ol1[j] = ll[d_in][mq * 16 + 8 + j];
  }
  *(u16x8*)(Whi + orow) = oh0;
  *(u16x8*)(Whi + orow + 8) = oh1;
  *(u16x8*)(Wlo + orow) = ol0;
  *(u16x8*)(Wlo + orow + 8) = ol1;
}

// W_O[e][m] fp32 -> Wt[m][e] bf16 via LDS transpose. grid 256 = et(16) x mt(16).
__global__ __launch_bounds__(256) void pack_wo_t(const float* __restrict__ WO,
                                                 u16* __restrict__ Wt) {
  __shared__ u16 lt[64][72];
  int blk = blockIdx.x;
  int mt = blk & 15, et = blk >> 4;
  int e_in = threadIdx.x >> 2, mq = threadIdx.x & 3;
  const f32x4* sp4 = (const f32x4*)(WO + (size_t)(et * 64 + e_in) * DMODEL + mt * 64 + mq * 16);
#pragma unroll
  for (int v4 = 0; v4 < 4; ++v4) {
    f32x4 a = sp4[v4];
#pragma unroll
    for (int j = 0; j < 4; ++j)
      lt[mq * 16 + v4 * 4 + j][e_in] = f2bf(a[j]);
  }
  __syncthreads();
  int m_in = threadIdx.x >> 2, eq = threadIdx.x & 3;
  size_t orow = (size_t)(mt * 64 + m_in) * DMODEL + et * 64 + eq * 16;
  u16x8 o0, o1;
#pragma unroll
  for (int j = 0; j < 8; ++j) {
    o0[j] = lt[m_in][eq * 16 + j];
    o1[j] = lt[m_in][eq * 16 + 8 + j];
  }
  *(u16x8*)(Wt + orow) = o0;
  *(u16x8*)(Wt + orow + 8) = o1;
}

// ---------------- split-precision GEMM for Q,K ----------------
__global__ __launch_bounds__(256, 2) void gemm_qk(
    const u16* __restrict__ Ahi, const u16* __restrict__ Alo,
    const u16* __restrict__ Bhi, const u16* __restrict__ Blo,
    const float* __restrict__ bq, const float* __restrict__ bk,
    u16* __restrict__ Qhi, u16* __restrict__ Qlo,
    u16* __restrict__ Khi, u16* __restrict__ Klo) {
  __shared__ u16 lds[2][16384];  // [buf][Ahi|Alo|Bhi|Blo] 4096 u16 each
  const int tid = threadIdx.x;
  const int wid = tid >> 6, lane = tid & 63, lr = lane & 15, lg = lane >> 4;
  const int wr = wid >> 1, wc = wid & 1;
  const int brow = blockIdx.y * 128, bcol = blockIdx.x * 128;

  f32x4 acc[4][4];
#pragma unroll
  for (int i = 0; i < 4; ++i)
#pragma unroll
    for (int j = 0; j < 4; ++j) acc[i][j] = (f32x4){0.f, 0.f, 0.f, 0.f};

#define STAGE_QK(buf, kt)                                                   \
  {                                                                         \
    _Pragma("unroll") for (int i = 0; i < 2; ++i) {                         \
      int idx = tid + i * 256;                                              \
      size_t go = (size_t)(brow + (idx >> 2)) * 1024 + (kt) * 32 + (idx & 3) * 8; \
      gload_lds16(Ahi + go, (char*)&lds[buf][0] + (wid * 64 + i * 256) * 16);     \
      gload_lds16(Alo + go, (char*)&lds[buf][4096] + (wid * 64 + i * 256) * 16);  \
    }                                                                       \
    _Pragma("unroll") for (int i = 0; i < 2; ++i) {                         \
      int idx = tid + i * 256;                                              \
      size_t go = (size_t)(bcol + (idx >> 2)) * 1024 + (kt) * 32 + (idx & 3) * 8; \
      gload_lds16(Bhi + go, (char*)&lds[buf][8192] + (wid * 64 + i * 256) * 16);  \
      gload_lds16(Blo + go, (char*)&lds[buf][12288] + (wid * 64 + i * 256) * 16); \
    }                                                                       \
  }

  STAGE_QK(0, 0);
  __syncthreads();
  int cur = 0;
  for (int kt = 0; kt < 32; ++kt) {
    if (kt + 1 < 32) STAGE_QK(cur ^ 1, kt + 1);
    const u16* LAh = &lds[cur][0];
    const u16* LAl = &lds[cur][4096];
    const u16* LBh = &lds[cur][8192];
    const u16* LBl = &lds[cur][12288];
    s16x8 ah[4], al[4], bh[4], bl[4];
#pragma unroll
    for (int ar = 0; ar < 4; ++ar) {
      int off = (wr * 64 + ar * 16 + lr) * 32 + lg * 8;
      ah[ar] = *(const s16x8*)(LAh + off);
      al[ar] = *(const s16x8*)(LAl + off);
    }
#pragma unroll
    for (int bc = 0; bc < 4; ++bc) {
      int off = (wc * 64 + bc * 16 + lr) * 32 + lg * 8;
      bh[bc] = *(const s16x8*)(LBh + off);
      bl[bc] = *(const s16x8*)(LBl + off);
    }
#pragma unroll
    for (int ar = 0; ar < 4; ++ar)
#pragma unroll
      for (int bc = 0; bc < 4; ++bc) {
        acc[ar][bc] = __builtin_amdgcn_mfma_f32_16x16x32_bf16(ah[ar], bh[bc], acc[ar][bc], 0, 0, 0);
        acc[ar][bc] = __builtin_amdgcn_mfma_f32_16x16x32_bf16(al[ar], bh[bc], acc[ar][bc], 0, 0, 0);
        acc[ar][bc] = __builtin_amdgcn_mfma_f32_16x16x32_bf16(ah[ar], bl[bc], acc[ar][bc], 0, 0, 0);
      }
    __syncthreads();
    cur ^= 1;
  }
#undef STAGE_QK

#pragma unroll
  for (int ar = 0; ar < 4; ++ar) {
    int row0 = brow + wr * 64 + ar * 16 + lg * 4;
    int bb = row0 >> 11, s0 = row0 & 2047;
#pragma unroll
    for (int bc = 0; bc < 4; ++bc) {
      int n = bcol + wc * 64 + bc * 16 + lr;
      int qk = n >> 10, hd = n & 1023, h = hd >> 6, d = hd & 63;
      float bias = (qk ? bk : bq)[hd];
      u16* Dhi = qk ? Khi : Qhi;
      u16* Dlo = qk ? Klo : Qlo;
      size_t base = ((size_t)(bb * NHEADS + h) * SEQ + s0) * DHEAD + d;
#pragma unroll
      for (int r = 0; r < 4; ++r) {
        float v = acc[ar][bc][r] + bias;
        if (qk == 0) v *= SCQ;         // fold softmax scale into Q
        u16 hh = f2bf(v);
        Dhi[base + (size_t)r * DHEAD] = hh;
        Dlo[base + (size_t)r * DHEAD] = f2bf(v - bf2f(hh));
      }
    }
  }
}

// ---------------- plain GEMM (V projection / out projection) ----------------
template <int EPI>
__global__ __launch_bounds__(256, 2) void gemm128(
    const u16* __restrict__ A, const u16* __restrict__ Bt,
    const float* __restrict__ bias_v, u16* __restrict__ Vto,
    const float* __restrict__ bo, float* __restrict__ Co) {
  __shared__ u16 lds[2][8192];
  const int tid = threadIdx.x;
  const int wid = tid >> 6, lane = tid & 63, lr = lane & 15, lg = lane >> 4;
  const int wr = wid >> 1, wc = wid & 1;
  const int brow = blockIdx.y * 128, bcol = blockIdx.x * 128;

  f32x4 acc[4][4];
#pragma unroll
  for (int i = 0; i < 4; ++i)
#pragma unroll
    for (int j = 0; j < 4; ++j) acc[i][j] = (f32x4){0.f, 0.f, 0.f, 0.f};

#define STAGE(buf, kt)                                                               \
  {                                                                                  \
    _Pragma("unroll") for (int i = 0; i < 2; ++i) {                                  \
      int idx = tid + i * 256;                                                       \
      gload_lds16(A + (size_t)(brow + (idx >> 2)) * 1024 + (kt) * 32 + (idx & 3) * 8,\
                  (char*)&lds[buf][0] + (wid * 64 + i * 256) * 16);                  \
    }                                                                                \
    _Pragma("unroll") for (int i = 0; i < 2; ++i) {                                  \
      int idx = tid + i * 256;                                                       \
      gload_lds16(Bt + (size_t)(bcol + (idx >> 2)) * 1024 + (kt) * 32 + (idx & 3) * 8,\
                  (char*)&lds[buf][4096] + (wid * 64 + i * 256) * 16);               \
    }                                                                                \
  }

  STAGE(0, 0);
  __syncthreads();
  int cur = 0;
  for (int kt = 0; kt < 32; ++kt) {
    if (kt + 1 < 32) STAGE(cur ^ 1, kt + 1);
    const u16* Ab = &lds[cur][0];
    const u16* Bb = &lds[cur][4096];
    s16x8 a[4], b[4];
#pragma unroll
    for (int ar = 0; ar < 4; ++ar)
      a[ar] = *(const s16x8*)(Ab + (wr * 64 + ar * 16 + lr) * 32 + lg * 8);
#pragma unroll
    for (int bc = 0; bc < 4; ++bc)
      b[bc] = *(const s16x8*)(Bb + (wc * 64 + bc * 16 + lr) * 32 + lg * 8);
#pragma unroll
    for (int ar = 0; ar < 4; ++ar)
#pragma unroll
      for (int bc = 0; bc < 4; ++bc)
        acc[ar][bc] = __builtin_amdgcn_mfma_f32_16x16x32_bf16(a[ar], b[bc], acc[ar][bc], 0, 0, 0);
    __syncthreads();
    cur ^= 1;
  }
#undef STAGE

#pragma unroll
  for (int ar = 0; ar < 4; ++ar) {
    int row0 = brow + wr * 64 + ar * 16 + lg * 4;
    int bb = row0 >> 11, s0 = row0 & 2047;
#pragma unroll
    for (int bc = 0; bc < 4; ++bc) {
      int n = bcol + wc * 64 + bc * 16 + lr;
      if (EPI == 0) {
        int h = n >> 6, d = n & 63;
        float bias = bias_v[n];
        u16x4 o;
        o[0] = f2bf(acc[ar][bc][0] + bias);
        o[1] = f2bf(acc[ar][bc][1] + bias);
        o[2] = f2bf(acc[ar][bc][2] + bias);
        o[3] = f2bf(acc[ar][bc][3] + bias);
        *(u16x4*)(Vto + ((size_t)(bb * NHEADS + h) * DHEAD + d) * SEQ + s0) = o;
      } else {
        float bias = bo[n];
#pragma unroll
        for (int r = 0; r < 4; ++r)
          Co[(size_t)(row0 + r) * DMODEL + n] = acc[ar][bc][r] + bias;
      }
    }
  }
}

// ---------------- flash attention: 8 waves, swapped QK^T, per-lane softmax ----------------
// grid 512 blocks x 512 threads. Block = (p, bh): waves 0-3 -> q-tile tA=31-p,
// waves 4-7 -> q-tile tB=p; shared K/V staging over kt=0..tA.
// bid layout groups all 16 p-blocks of one bh on the same XCD (bid%8 = bh%8).
// LDS 56KB: kbuf[2] (Khi 8K|Klo 8K each) @0/@16384, vbuf @32768, P @40960 (2K/wave).
__global__ __launch_bounds__(512, 4) void attn_kernel(
    const u16* __restrict__ Qhi, const u16* __restrict__ Qlo,
    const u16* __restrict__ Khi, const u16* __restrict__ Klo,
    const u16* __restrict__ Vt, u16* __restrict__ MH) {
  __shared__ u16 sh[28672];   // 56 KB
  const int tid = threadIdx.x, wid = tid >> 6, lane = tid & 63;
  const int lr = lane & 15, lg = lane >> 4;
  const int g = wid >> 2, ww = wid & 3;
  const int bid = blockIdx.x;
  const int x = bid & 7, y = bid >> 3;
  const int bh = x + 8 * (y & 3);
  const int p = y >> 2;                  // heavy pairs dispatched first
  const int h = bh & 15, b = bh >> 4;
  const int tA = 31 - p, tB = p;
  const int tg = g ? tB : tA;
  const u16* Qhb = Qhi + (size_t)bh * (SEQ * DHEAD);
  const u16* Qlb = Qlo + (size_t)bh * (SEQ * DHEAD);
  const u16* Khb = Khi + (size_t)bh * (SEQ * DHEAD);
  const u16* Klb = Klo + (size_t)bh * (SEQ * DHEAD);
  const u16* Vb  = Vt  + (size_t)bh * (DHEAD * SEQ);

  const int srow = tid >> 3, sseg = (tid & 7) ^ (srow & 7);   // pre-swizzled source

#define KSTAGE(bufbyte, kt)                                                     \
  {                                                                             \
    size_t ko = (size_t)((kt) * 64 + srow) * DHEAD + sseg * 8;                  \
    gload_lds16(Khb + ko, (char*)sh + (bufbyte) + tid * 16);                    \
    gload_lds16(Klb + ko, (char*)sh + (bufbyte) + 8192 + tid * 16);             \
  }
#define VSTAGE(kt)                                                              \
  gload_lds16(Vb + (size_t)srow * SEQ + (kt) * 64 + sseg * 8,                   \
              (char*)sh + 32768 + tid * 16);

  // prologue: Q tiles into (kbuf1, vbuf, P) regions + K(0)
  {
    size_t qoA = (size_t)(tA * 64 + srow) * DHEAD + sseg * 8;
    size_t qoB = (size_t)(tB * 64 + srow) * DHEAD + sseg * 8;
    gload_lds16(Qhb + qoA, (char*)sh + 16384 + tid * 16);
    gload_lds16(Qlb + qoA, (char*)sh + 24576 + tid * 16);
    gload_lds16(Qhb + qoB, (char*)sh + 32768 + tid * 16);
    gload_lds16(Qlb + qoB, (char*)sh + 40960 + tid * 16);
    KSTAGE(0, 0);
  }
  __syncthreads();

  s16x8 qfh[2], qfl[2];
  {
    const int hbase = g ? 32768 : 16384, lbase = g ? 40960 : 24576;
    const int row = ww * 16 + lr;
#pragma unroll
    for (int ks = 0; ks < 2; ++ks) {
      int off = (row * 128 + (ks * 4 + lg) * 16) ^ ((row & 7) << 4);
      qfh[ks] = *(const s16x8*)((const char*)sh + hbase + off);
      qfl[ks] = *(const s16x8*)((const char*)sh + lbase + off);
    }
  }
  __syncthreads();
  VSTAGE(0);
  if (tA >= 1) KSTAGE(16384, 1);

  f32x4 acc_o[4];
#pragma unroll
  for (int z = 0; z < 4; ++z) acc_o[z] = (f32x4){0.f, 0.f, 0.f, 0.f};
  float m = -1e30f, l = 0.f;
  const int qlane = tg * 64 + ww * 16 + lr;
  char* pbase = (char*)sh + 40960 + wid * 2048;
  int cur = 0;

  for (int kt = 0; kt <= tA; ++kt) {
    const bool act = (kt <= tg);
    const bool dg = (kt == tg);
    const char* kb = (const char*)sh + cur * 16384;

    if (act) {
      f32x4 s4[4];
#pragma unroll
      for (int cb = 0; cb < 4; ++cb) s4[cb] = (f32x4){0.f, 0.f, 0.f, 0.f};
      __builtin_amdgcn_s_setprio(1);
#pragma unroll
      for (int ks = 0; ks < 2; ++ks)
#pragma unroll
        for (int cb = 0; cb < 4; ++cb) {
          int row = cb * 16 + lr;
          int off = (row * 128 + (ks * 4 + lg) * 16) ^ ((row & 7) << 4);
          s16x8 kbh = *(const s16x8*)(kb + off);
          s16x8 kbl = *(const s16x8*)(kb + 8192 + off);
          // swapped: S^T = K·Q^T  -> lane owns one q row (q = qlane)
          s4[cb] = __builtin_amdgcn_mfma_f32_16x16x32_bf16(kbh, qfh[ks], s4[cb], 0, 0, 0);
          s4[cb] = __builtin_amdgcn_mfma_f32_16x16x32_bf16(kbh, qfl[ks], s4[cb], 0, 0, 0);
          s4[cb] = __builtin_amdgcn_mfma_f32_16x16x32_bf16(kbl, qfh[ks], s4[cb], 0, 0, 0);
        }
      __builtin_amdgcn_s_setprio(0);

      // per-lane online softmax over this lane's 16 k-values (q = qlane)
      float tv[4][4];
#pragma unroll
      for (int cb = 0; cb < 4; ++cb)
#pragma unroll
        for (int r = 0; r < 4; ++r) {
          float v = s4[cb][r];
          if (dg && (kt * 64 + cb * 16 + lg * 4 + r > qlane)) v = -1e30f;
          tv[cb][r] = v;
        }
      float tm = tv[0][0];
#pragma unroll
      for (int cb = 0; cb < 4; ++cb)
#pragma unroll
        for (int r = 0; r < 4; ++r) tm = fmaxf(tm, tv[cb][r]);
      tm = fmaxf(tm, __shfl_xor(tm, 16));
      tm = fmaxf(tm, __shfl_xor(tm, 32));
      float m2 = fmaxf(m, tm);
      float al = exp2f(m - m2);
      m = m2;

      float pp[4][4];
      float rs = 0.f;
#pragma unroll
      for (int cb = 0; cb < 4; ++cb)
#pragma unroll
        for (int r = 0; r < 4; ++r) {
          float pv = exp2f(tv[cb][r] - m2);
          pp[cb][r] = pv;
          rs += pv;
        }
      rs += __shfl_xor(rs, 16);
      rs += __shfl_xor(rs, 32);
      l = l * al + rs;

      // rescale accumulator (acc rows are q_local = lg*4+rr -> alpha from lane lg*4+rr)
#pragma unroll
      for (int rr = 0; rr < 4; ++rr) {
        float ar = __shfl(al, (lg << 2) | rr);
#pragma unroll
        for (int db = 0; db < 4; ++db) acc_o[db][rr] *= ar;
      }

      // pack P row (q = lr) into p_lds[16][64] bf16, swizzled
#pragma unroll
      for (int cb = 0; cb < 4; ++cb) {
        u32x2 w;
        w[0] = (unsigned)f2bf(pp[cb][0]) | ((unsigned)f2bf(pp[cb][1]) << 16);
        w[1] = (unsigned)f2bf(pp[cb][2]) | ((unsigned)f2bf(pp[cb][3]) << 16);
        int off = (lr * 128 + cb * 32 + lg * 8) ^ ((lr & 7) << 4);
        *(u32x2*)(pbase + off) = w;
      }
    }

    __syncthreads();   // V(kt) + K(kt+1) landed; everyone past QK reads

    if (act) {
      __builtin_amdgcn_s_setprio(1);
#pragma unroll
      for (int ks = 0; ks < 2; ++ks) {
        s16x8 pa = *(const s16x8*)(pbase + ((lr * 128 + lg * 16 + ks * 64) ^ ((lr & 7) << 4)));
#pragma unroll
        for (int db = 0; db < 4; ++db) {
          int vrow = db * 16 + lr;
          s16x8 vb = *(const s16x8*)((const char*)sh + 32768 +
                                     ((vrow * 128 + lg * 16 + ks * 64) ^ ((vrow & 7) << 4)));
          acc_o[db] = __builtin_amdgcn_mfma_f32_16x16x32_bf16(pa, vb, acc_o[db], 0, 0, 0);
        }
      }
      __builtin_amdgcn_s_setprio(0);

      if (dg) {
        float lb[4];
#pragma unroll
        for (int rr = 0; rr < 4; ++rr) lb[rr] = __shfl(l, (lg << 2) | rr);
#pragma unroll
        for (int db = 0; db < 4; ++db)
#pragma unroll
          for (int rr = 0; rr < 4; ++rr) {
            int qrow = tg * 64 + ww * 16 + lg * 4 + rr;
            MH[((size_t)(b * SEQ + qrow)) * DMODEL + h * DHEAD + db * 16 + lr] =
                f2bf(acc_o[db][rr] / lb[rr]);
          }
      }
    }

    __syncthreads();   // all waves done with vbuf + kbuf[cur]

    if (kt + 2 <= tA) KSTAGE(cur * 16384, kt + 2);
    if (kt + 1 <= tA) VSTAGE(kt + 1);
    cur ^= 1;
  }
#undef KSTAGE
#undef VSTAGE
}

// ---------------- launcher ----------------
extern "C" void kernel_launch(void* const* d_in, const int* in_sizes, int n_in,
                              void* d_out, int out_size, void* d_ws, size_t ws_size,
                              hipStream_t stream) {
  const float* residual = (const float*)d_in[0];
  const float* WQ = (const float*)d_in[1];
  const float* WK = (const float*)d_in[2];
  const float* WV = (const float*)d_in[3];
  const float* WO = (const float*)d_in[4];
  const float* bQ = (const float*)d_in[5];
  const float* bK = (const float*)d_in[6];
  const float* bV = (const float*)d_in[7];
  const float* bO = (const float*)d_in[8];
  float* out = (float*)d_out;

  char* w = (char*)d_ws;
  u16* Xhi = (u16*)(w);                        // 8 MB  [4096][1024]
  u16* Xlo = (u16*)(w + ((size_t)8 << 20));    // 8 MB
  u16* Whi = (u16*)(w + ((size_t)16 << 20));   // 6 MB  [3072][1024]
  u16* Wlo = (u16*)(w + ((size_t)22 << 20));   // 6 MB
  u16* Wo  = (u16*)(w + ((size_t)28 << 20));   // 2 MB  [1024][1024]
  u16* Qhi = (u16*)(w + ((size_t)30 << 20));   // 8 MB  [32][2048][64]
  u16* Qlo = (u16*)(w + ((size_t)38 << 20));   // 8 MB
  u16* Khi = (u16*)(w + ((size_t)46 << 20));   // 8 MB
  u16* Klo = (u16*)(w + ((size_t)54 << 20));   // 8 MB
  u16* Vtd = (u16*)(w + ((size_t)62 << 20));   // 8 MB  [32][64][2048]
  u16* MH  = (u16*)(w + ((size_t)8 << 20));    // aliases Xlo (dead after gemm_qk)

  pack_x_kernel<<<2048, 256, 0, stream>>>(residual, Xhi, Xlo);
  pack_wqkv_t<<<768, 256, 0, stream>>>(WQ, WK, WV, Whi, Wlo);
  pack_wo_t<<<256, 256, 0, stream>>>(WO, Wo);

  gemm_qk<<<dim3(NQK / 128, MROWS / 128), 256, 0, stream>>>(
      Xhi, Xlo, Whi, Wlo, bQ, bK, Qhi, Qlo, Khi, Klo);

  gemm128<0><<<dim3(DMODEL / 128, MROWS / 128), 256, 0, stream>>>(
      Xhi, Whi + (size_t)NQK * DMODEL, bV, Vtd, nullptr, nullptr);

  attn_kernel<<<512, 512, 0, stream>>>(Qhi, Qlo, Khi, Klo, Vtd, MH);

  gemm128<1><<<dim3(DMODEL / 128, MROWS / 128), 256, 0, stream>>>(
      MH, Wo, nullptr, nullptr, bO, out);
}

// Round 5
// 119.724 us; speedup vs baseline: 2.3874x; 1.4752x over previous
//
#include <hip/hip_runtime.h>
#include <stdint.h>

typedef unsigned short u16;
typedef _Float16 f16;
typedef __attribute__((ext_vector_type(8))) _Float16 f16x8;   // 8 fp16 MFMA frag
typedef __attribute__((ext_vector_type(4))) float f32x4;      // MFMA accumulator
typedef __attribute__((ext_vector_type(4))) unsigned short u16x4;
typedef __attribute__((ext_vector_type(8))) unsigned short u16x8;
typedef __attribute__((ext_vector_type(2))) unsigned u32x2;

#define NHEADS 16
#define DMODEL 1024
#define DHEAD 64
#define SEQ 2048
#define NBATCH 2
#define MROWS (NBATCH * SEQ)   /* 4096 */
#define NQKV 3072
#define SCQ 0.18033688011112042f   /* (1/8) * log2(e), folded into Q */

__device__ __forceinline__ u16 f2h(float x) {
  union { f16 h; u16 u; } v;
  v.h = (f16)x;                  // v_cvt_f16_f32, RNE
  return v.u;
}

__device__ __forceinline__ void gload_lds16(const void* g, void* l) {
  __builtin_amdgcn_global_load_lds(
      (const __attribute__((address_space(1))) void*)g,
      (__attribute__((address_space(3))) void*)l, 16, 0, 0);
}

// ---------------- merged prep kernel ----------------
// blocks [0,2048): X fp32 -> fp16            (8 elems/thread)
// blocks [2048,2816): W_QKV transpose->fp16  (LDS transpose, coalesced)
// blocks [2816,3072): W_O transpose->fp16
__global__ __launch_bounds__(256) void prep_kernel(
    const float* __restrict__ X,
    const float* __restrict__ WQ, const float* __restrict__ WK,
    const float* __restrict__ WV, const float* __restrict__ WO,
    u16* __restrict__ Xh, u16* __restrict__ Wqkv, u16* __restrict__ Wo) {
  __shared__ u16 lt[64][72];
  int blk = blockIdx.x;
  if (blk < 2048) {
    int i = blk * 256 + threadIdx.x;
    const f32x4* xv = (const f32x4*)(X + (size_t)i * 8);
    f32x4 a = xv[0], b = xv[1];
    u16x8 o;
    o[0] = f2h(a[0]); o[1] = f2h(a[1]); o[2] = f2h(a[2]); o[3] = f2h(a[3]);
    o[4] = f2h(b[0]); o[5] = f2h(b[1]); o[6] = f2h(b[2]); o[7] = f2h(b[3]);
    *(u16x8*)(Xh + (size_t)i * 8) = o;
  } else if (blk < 2816) {
    // W[h][m][d] -> Wqkv[n][m], n = qkv*1024 + h*64 + d
    int bb = blk - 2048;
    int mt = bb & 15, hh = (bb >> 4) & 15, qkv = bb >> 8;
    const float* W = (qkv == 0) ? WQ : (qkv == 1) ? WK : WV;
    int m_in = threadIdx.x >> 2, dq = threadIdx.x & 3;
    const f32x4* sp4 = (const f32x4*)(W + (size_t)hh * (DMODEL * DHEAD) +
                                      (size_t)(mt * 64 + m_in) * DHEAD + dq * 16);
#pragma unroll
    for (int v4 = 0; v4 < 4; ++v4) {
      f32x4 a = sp4[v4];
#pragma unroll
      for (int j = 0; j < 4; ++j) lt[dq * 16 + v4 * 4 + j][m_in] = f2h(a[j]);
    }
    __syncthreads();
    int d_in = threadIdx.x >> 2, mq = threadIdx.x & 3;
    size_t orow = ((size_t)(qkv * 1024 + hh * 64 + d_in)) * DMODEL + mt * 64 + mq * 16;
    u16x8 o0, o1;
#pragma unroll
    for (int j = 0; j < 8; ++j) {
      o0[j] = lt[d_in][mq * 16 + j];
      o1[j] = lt[d_in][mq * 16 + 8 + j];
    }
    *(u16x8*)(Wqkv + orow) = o0;
    *(u16x8*)(Wqkv + orow + 8) = o1;
  } else {
    // WO[e][m] -> Wo[m][e]
    int bb = blk - 2816;
    int mt = bb & 15, et = bb >> 4;
    int e_in = threadIdx.x >> 2, mq = threadIdx.x & 3;
    const f32x4* sp4 = (const f32x4*)(WO + (size_t)(et * 64 + e_in) * DMODEL + mt * 64 + mq * 16);
#pragma unroll
    for (int v4 = 0; v4 < 4; ++v4) {
      f32x4 a = sp4[v4];
#pragma unroll
      for (int j = 0; j < 4; ++j) lt[mq * 16 + v4 * 4 + j][e_in] = f2h(a[j]);
    }
    __syncthreads();
    int m_in = threadIdx.x >> 2, eq = threadIdx.x & 3;
    size_t orow = (size_t)(mt * 64 + m_in) * DMODEL + et * 64 + eq * 16;
    u16x8 o0, o1;
#pragma unroll
    for (int j = 0; j < 8; ++j) {
      o0[j] = lt[m_in][eq * 16 + j];
      o1[j] = lt[m_in][eq * 16 + 8 + j];
    }
    *(u16x8*)(Wo + orow) = o0;
    *(u16x8*)(Wo + orow + 8) = o1;
  }
}

// ---------------- QKV projection GEMM (fp16, N=3072, fused epilogue) ----------------
// C[M][N] = A[M][K] Bt[N][K]^T; Q gets (.+bias)*SCQ -> [bh][s][d];
// K -> [bh][s][d]; V -> transposed [bh][d][s].
__global__ __launch_bounds__(256, 2) void gemm_qkv(
    const u16* __restrict__ A, const u16* __restrict__ Bt,
    const float* __restrict__ bq, const float* __restrict__ bk, const float* __restrict__ bv,
    u16* __restrict__ Qo, u16* __restrict__ Ko, u16* __restrict__ Vto) {
  __shared__ u16 lds[2][8192];
  const int tid = threadIdx.x;
  const int wid = tid >> 6, lane = tid & 63, lr = lane & 15, lg = lane >> 4;
  const int wr = wid >> 1, wc = wid & 1;
  const int brow = blockIdx.y * 128, bcol = blockIdx.x * 128;

  f32x4 acc[4][4];
#pragma unroll
  for (int i = 0; i < 4; ++i)
#pragma unroll
    for (int j = 0; j < 4; ++j) acc[i][j] = (f32x4){0.f, 0.f, 0.f, 0.f};

#define STAGE(buf, kt)                                                               \
  {                                                                                  \
    _Pragma("unroll") for (int i = 0; i < 2; ++i) {                                  \
      int idx = tid + i * 256;                                                       \
      gload_lds16(A + (size_t)(brow + (idx >> 2)) * 1024 + (kt) * 32 + (idx & 3) * 8,\
                  (char*)&lds[buf][0] + (wid * 64 + i * 256) * 16);                  \
    }                                                                                \
    _Pragma("unroll") for (int i = 0; i < 2; ++i) {                                  \
      int idx = tid + i * 256;                                                       \
      gload_lds16(Bt + (size_t)(bcol + (idx >> 2)) * 1024 + (kt) * 32 + (idx & 3) * 8,\
                  (char*)&lds[buf][4096] + (wid * 64 + i * 256) * 16);               \
    }                                                                                \
  }

  STAGE(0, 0);
  __syncthreads();
  int cur = 0;
  for (int kt = 0; kt < 32; ++kt) {
    if (kt + 1 < 32) STAGE(cur ^ 1, kt + 1);
    const u16* Ab = &lds[cur][0];
    const u16* Bb = &lds[cur][4096];
    f16x8 a[4], b[4];
#pragma unroll
    for (int ar = 0; ar < 4; ++ar)
      a[ar] = *(const f16x8*)(Ab + (wr * 64 + ar * 16 + lr) * 32 + lg * 8);
#pragma unroll
    for (int bc = 0; bc < 4; ++bc)
      b[bc] = *(const f16x8*)(Bb + (wc * 64 + bc * 16 + lr) * 32 + lg * 8);
#pragma unroll
    for (int ar = 0; ar < 4; ++ar)
#pragma unroll
      for (int bc = 0; bc < 4; ++bc)
        acc[ar][bc] = __builtin_amdgcn_mfma_f32_16x16x32_f16(a[ar], b[bc], acc[ar][bc], 0, 0, 0);
    __syncthreads();
    cur ^= 1;
  }

#pragma unroll
  for (int ar = 0; ar < 4; ++ar) {
    int row0 = brow + wr * 64 + ar * 16 + lg * 4;
    int bb = row0 >> 11, s0 = row0 & 2047;
#pragma unroll
    for (int bc = 0; bc < 4; ++bc) {
      int n = bcol + wc * 64 + bc * 16 + lr;
      int qkv = n >> 10, hd = n & 1023, h = hd >> 6, d = hd & 63;
      float bias = ((qkv == 0) ? bq : (qkv == 1) ? bk : bv)[hd];
      if (qkv < 2) {
        u16* dst = qkv ? Ko : Qo;
        float sc = qkv ? 1.f : SCQ;
        size_t base = ((size_t)(bb * NHEADS + h) * SEQ + s0) * DHEAD + d;
#pragma unroll
        for (int r = 0; r < 4; ++r)
          dst[base + (size_t)r * DHEAD] = f2h((acc[ar][bc][r] + bias) * sc);
      } else {
        u16x4 o;
        o[0] = f2h(acc[ar][bc][0] + bias);
        o[1] = f2h(acc[ar][bc][1] + bias);
        o[2] = f2h(acc[ar][bc][2] + bias);
        o[3] = f2h(acc[ar][bc][3] + bias);
        *(u16x4*)(Vto + ((size_t)(bb * NHEADS + h) * DHEAD + d) * SEQ + s0) = o;
      }
    }
  }
}

// ---------------- out-projection GEMM (fp16 in, fp32 out) ----------------
__global__ __launch_bounds__(256, 2) void gemm_out(
    const u16* __restrict__ A, const u16* __restrict__ Bt,
    const float* __restrict__ bo, float* __restrict__ Co) {
  __shared__ u16 lds[2][8192];
  const int tid = threadIdx.x;
  const int wid = tid >> 6, lane = tid & 63, lr = lane & 15, lg = lane >> 4;
  const int wr = wid >> 1, wc = wid & 1;
  const int brow = blockIdx.y * 128, bcol = blockIdx.x * 128;

  f32x4 acc[4][4];
#pragma unroll
  for (int i = 0; i < 4; ++i)
#pragma unroll
    for (int j = 0; j < 4; ++j) acc[i][j] = (f32x4){0.f, 0.f, 0.f, 0.f};

  STAGE(0, 0);
  __syncthreads();
  int cur = 0;
  for (int kt = 0; kt < 32; ++kt) {
    if (kt + 1 < 32) STAGE(cur ^ 1, kt + 1);
    const u16* Ab = &lds[cur][0];
    const u16* Bb = &lds[cur][4096];
    f16x8 a[4], b[4];
#pragma unroll
    for (int ar = 0; ar < 4; ++ar)
      a[ar] = *(const f16x8*)(Ab + (wr * 64 + ar * 16 + lr) * 32 + lg * 8);
#pragma unroll
    for (int bc = 0; bc < 4; ++bc)
      b[bc] = *(const f16x8*)(Bb + (wc * 64 + bc * 16 + lr) * 32 + lg * 8);
#pragma unroll
    for (int ar = 0; ar < 4; ++ar)
#pragma unroll
      for (int bc = 0; bc < 4; ++bc)
        acc[ar][bc] = __builtin_amdgcn_mfma_f32_16x16x32_f16(a[ar], b[bc], acc[ar][bc], 0, 0, 0);
    __syncthreads();
    cur ^= 1;
  }
#undef STAGE

#pragma unroll
  for (int ar = 0; ar < 4; ++ar) {
    int row0 = brow + wr * 64 + ar * 16 + lg * 4;
#pragma unroll
    for (int bc = 0; bc < 4; ++bc) {
      int n = bcol + wc * 64 + bc * 16 + lr;
      float bias = bo[n];
#pragma unroll
      for (int r = 0; r < 4; ++r)
        Co[(size_t)(row0 + r) * DMODEL + n] = acc[ar][bc][r] + bias;
    }
  }
}

// ---------------- flash attention: fp16, 1-term QK, full dbuf, 1 barrier/iter ----------------
// grid 512 x 512 thr. Block = (p, bh): waves 0-3 -> tile tA=31-p, waves 4-7 -> tB=p.
// LDS 48KB: k0@0, k1@8192, v0@16384, v1@24576 (8KB each), P@32768 (2KB/wave).
__global__ __launch_bounds__(512, 4) void attn_kernel(
    const u16* __restrict__ Q, const u16* __restrict__ K,
    const u16* __restrict__ Vt, u16* __restrict__ MH) {
  __shared__ u16 sh[24576];   // 48 KB
  char* sh8 = (char*)sh;
  const int tid = threadIdx.x, wid = tid >> 6, lane = tid & 63;
  const int lr = lane & 15, lg = lane >> 4;
  const int g = wid >> 2, ww = wid & 3;
  const int bid = blockIdx.x;
  const int x = bid & 7, y = bid >> 3;
  const int bh = x + 8 * (y & 3);
  const int p = y >> 2;                  // heavy pairs dispatched first
  const int h = bh & 15, b = bh >> 4;
  const int tA = 31 - p, tB = p;
  const int tg = g ? tB : tA;
  const u16* Qb = Q + (size_t)bh * (SEQ * DHEAD);
  const u16* Kb = K + (size_t)bh * (SEQ * DHEAD);
  const u16* Vb = Vt + (size_t)bh * (DHEAD * SEQ);

  const int srow = tid >> 3, sseg = (tid & 7) ^ (srow & 7);   // pre-swizzled source

#define KSTAGE(bufbyte, kt)                                              \
  gload_lds16(Kb + (size_t)((kt) * 64 + srow) * DHEAD + sseg * 8,        \
              sh8 + (bufbyte) + tid * 16);
#define VSTAGE(bufbyte, kt)                                              \
  gload_lds16(Vb + (size_t)srow * SEQ + (kt) * 64 + sseg * 8,            \
              sh8 + (bufbyte) + tid * 16);

  // prologue: QA -> k1 region, QB -> v1 region, K(0) -> k0, V(0) -> v0
  {
    gload_lds16(Qb + (size_t)(tA * 64 + srow) * DHEAD + sseg * 8, sh8 + 8192 + tid * 16);
    gload_lds16(Qb + (size_t)(tB * 64 + srow) * DHEAD + sseg * 8, sh8 + 24576 + tid * 16);
    KSTAGE(0, 0);
    VSTAGE(16384, 0);
  }
  __syncthreads();

  f16x8 qf[2];
  {
    const int base = g ? 24576 : 8192;
    const int row = ww * 16 + lr;
#pragma unroll
    for (int ks = 0; ks < 2; ++ks) {
      int off = (row * 128 + (ks * 4 + lg) * 16) ^ ((row & 7) << 4);
      qf[ks] = *(const f16x8*)(sh8 + base + off);
    }
  }
  __syncthreads();   // Q consumed; k1/v1 free for staging

  f32x4 acc_o[4];
#pragma unroll
  for (int z = 0; z < 4; ++z) acc_o[z] = (f32x4){0.f, 0.f, 0.f, 0.f};
  float m = -1e30f, l = 0.f;
  const int qlane = tg * 64 + ww * 16 + lr;
  char* pbase = sh8 + 32768 + wid * 2048;

  for (int kt = 0; kt <= tA; ++kt) {
    const int cur = kt & 1;
    if (kt + 1 <= tA) {
      KSTAGE((kt + 1) & 1 ? 8192 : 0, kt + 1);
      VSTAGE(((kt + 1) & 1) ? 24576 : 16384, kt + 1);
    }
    const bool act = (kt <= tg);
    const bool dg = (kt == tg);

    if (act) {
      const char* kb = sh8 + (cur ? 8192 : 0);
      f32x4 s4[4];
#pragma unroll
      for (int cb = 0; cb < 4; ++cb) s4[cb] = (f32x4){0.f, 0.f, 0.f, 0.f};
      __builtin_amdgcn_s_setprio(1);
#pragma unroll
      for (int ks = 0; ks < 2; ++ks)
#pragma unroll
        for (int cb = 0; cb < 4; ++cb) {
          int row = cb * 16 + lr;
          int off = (row * 128 + (ks * 4 + lg) * 16) ^ ((row & 7) << 4);
          f16x8 kf = *(const f16x8*)(kb + off);
          // swapped: S^T = K·Q^T -> lane owns one q row (q = qlane)
          s4[cb] = __builtin_amdgcn_mfma_f32_16x16x32_f16(kf, qf[ks], s4[cb], 0, 0, 0);
        }
      __builtin_amdgcn_s_setprio(0);

      float tv[4][4];
#pragma unroll
      for (int cb = 0; cb < 4; ++cb)
#pragma unroll
        for (int r = 0; r < 4; ++r) {
          float v = s4[cb][r];
          if (dg && (kt * 64 + cb * 16 + lg * 4 + r > qlane)) v = -1e30f;
          tv[cb][r] = v;
        }
      float tm = tv[0][0];
#pragma unroll
      for (int cb = 0; cb < 4; ++cb)
#pragma unroll
        for (int r = 0; r < 4; ++r) tm = fmaxf(tm, tv[cb][r]);
      tm = fmaxf(tm, __shfl_xor(tm, 16));
      tm = fmaxf(tm, __shfl_xor(tm, 32));

      // defer-max (T13): skip max-update + rescale while growth <= 8 (exp2-domain)
      if (__all(tm <= m + 8.f)) {
        float rs = 0.f, pp[4][4];
#pragma unroll
        for (int cb = 0; cb < 4; ++cb)
#pragma unroll
          for (int r = 0; r < 4; ++r) {
            float pv = exp2f(tv[cb][r] - m);
            pp[cb][r] = pv;
            rs += pv;
          }
        rs += __shfl_xor(rs, 16);
        rs += __shfl_xor(rs, 32);
        l += rs;
#pragma unroll
        for (int cb = 0; cb < 4; ++cb) {
          u32x2 w;
          w[0] = (unsigned)f2h(pp[cb][0]) | ((unsigned)f2h(pp[cb][1]) << 16);
          w[1] = (unsigned)f2h(pp[cb][2]) | ((unsigned)f2h(pp[cb][3]) << 16);
          *(u32x2*)(pbase + ((lr * 128 + cb * 32 + lg * 8) ^ ((lr & 7) << 4))) = w;
        }
      } else {
        float m2 = fmaxf(m, tm);
        float al = exp2f(m - m2);
        m = m2;
        float rs = 0.f, pp[4][4];
#pragma unroll
        for (int cb = 0; cb < 4; ++cb)
#pragma unroll
          for (int r = 0; r < 4; ++r) {
            float pv = exp2f(tv[cb][r] - m2);
            pp[cb][r] = pv;
            rs += pv;
          }
        rs += __shfl_xor(rs, 16);
        rs += __shfl_xor(rs, 32);
        l = l * al + rs;
#pragma unroll
        for (int rr = 0; rr < 4; ++rr) {
          float ar = __shfl(al, (lg << 2) | rr);
#pragma unroll
          for (int db = 0; db < 4; ++db) acc_o[db][rr] *= ar;
        }
#pragma unroll
        for (int cb = 0; cb < 4; ++cb) {
          u32x2 w;
          w[0] = (unsigned)f2h(pp[cb][0]) | ((unsigned)f2h(pp[cb][1]) << 16);
          w[1] = (unsigned)f2h(pp[cb][2]) | ((unsigned)f2h(pp[cb][3]) << 16);
          *(u32x2*)(pbase + ((lr * 128 + cb * 32 + lg * 8) ^ ((lr & 7) << 4))) = w;
        }
      }

      // O += P V   (V from vbuf[cur])
      const char* vbase = sh8 + (cur ? 24576 : 16384);
      __builtin_amdgcn_s_setprio(1);
#pragma unroll
      for (int ks = 0; ks < 2; ++ks) {
        f16x8 pa = *(const f16x8*)(pbase + ((lr * 128 + lg * 16 + ks * 64) ^ ((lr & 7) << 4)));
#pragma unroll
        for (int db = 0; db < 4; ++db) {
          int vrow = db * 16 + lr;
          f16x8 vv = *(const f16x8*)(vbase + ((vrow * 128 + lg * 16 + ks * 64) ^ ((vrow & 7) << 4)));
          acc_o[db] = __builtin_amdgcn_mfma_f32_16x16x32_f16(pa, vv, acc_o[db], 0, 0, 0);
        }
      }
      __builtin_amdgcn_s_setprio(0);

      if (dg) {
        float lb[4];
#pragma unroll
        for (int rr = 0; rr < 4; ++rr) lb[rr] = __shfl(l, (lg << 2) | rr);
#pragma unroll
        for (int db = 0; db < 4; ++db)
#pragma unroll
          for (int rr = 0; rr < 4; ++rr) {
            int qrow = tg * 64 + ww * 16 + lg * 4 + rr;
            MH[((size_t)(b * SEQ + qrow)) * DMODEL + h * DHEAD + db * 16 + lr] =
                f2h(acc_o[db][rr] / lb[rr]);
          }
      }
    }

    __syncthreads();   // drains next-tile loads; guards buffer reuse
  }
#undef KSTAGE
#undef VSTAGE
}

// ---------------- launcher ----------------
extern "C" void kernel_launch(void* const* d_in, const int* in_sizes, int n_in,
                              void* d_out, int out_size, void* d_ws, size_t ws_size,
                              hipStream_t stream) {
  const float* residual = (const float*)d_in[0];
  const float* WQ = (const float*)d_in[1];
  const float* WK = (const float*)d_in[2];
  const float* WV = (const float*)d_in[3];
  const float* WO = (const float*)d_in[4];
  const float* bQ = (const float*)d_in[5];
  const float* bK = (const float*)d_in[6];
  const float* bV = (const float*)d_in[7];
  const float* bO = (const float*)d_in[8];
  float* out = (float*)d_out;

  char* w = (char*)d_ws;
  u16* Xh   = (u16*)(w);                       // 8 MB  [4096][1024]
  u16* Wqkv = (u16*)(w + ((size_t)8 << 20));   // 6 MB  [3072][1024]
  u16* Wo   = (u16*)(w + ((size_t)14 << 20));  // 2 MB  [1024][1024]
  u16* Qd   = (u16*)(w + ((size_t)16 << 20));  // 8 MB  [32][2048][64]
  u16* Kd   = (u16*)(w + ((size_t)24 << 20));  // 8 MB  [32][2048][64]
  u16* Vtd  = (u16*)(w + ((size_t)32 << 20));  // 8 MB  [32][64][2048]
  u16* MH   = (u16*)(w + ((size_t)40 << 20));  // 8 MB  [4096][1024]

  prep_kernel<<<3072, 256, 0, stream>>>(residual, WQ, WK, WV, WO, Xh, Wqkv, Wo);

  gemm_qkv<<<dim3(NQKV / 128, MROWS / 128), 256, 0, stream>>>(
      Xh, Wqkv, bQ, bK, bV, Qd, Kd, Vtd);

  attn_kernel<<<512, 512, 0, stream>>>(Qd, Kd, Vtd, MH);

  gemm_out<<<dim3(DMODEL / 128, MROWS / 128), 256, 0, stream>>>(MH, Wo, bO, out);
}